// Round 5
// baseline (2226.068 us; speedup 1.0000x reference)
//
#include <hip/hip_runtime.h>
#include <hip/hip_bf16.h>

#define NN 50000
#define RR 8
#define EE 200000
#define EDD 400000
#define SCB 196   // ceil(NN/256) scan blocks

typedef __attribute__((ext_vector_type(8))) short short8;
typedef __attribute__((ext_vector_type(4))) float floatx4;

static __device__ __forceinline__ unsigned short f2bf(float f) {
    union { float f; unsigned u; } v; v.f = f;
    unsigned r = v.u + 0x7fff + ((v.u >> 16) & 1);
    return (unsigned short)(r >> 16);
}
static __device__ __forceinline__ float bf2f(unsigned short h) {
    union { unsigned u; float f; } v; v.u = ((unsigned)h) << 16;
    return v.f;
}
// async global->LDS, 16B per lane; LDS dest = uniform base + lane*16
static __device__ __forceinline__ void gload_lds16(const unsigned short* g, unsigned short* l) {
    __builtin_amdgcn_global_load_lds(
        (const __attribute__((address_space(1))) void*)g,
        (__attribute__((address_space(3))) void*)l,
        16, 0, 0);
}

// ---------------- LDS-privatized degree histogram ----------------
// grid (4 edge-chunks, RR, 4: z = which*2 + node-half). 16-bit packed LDS bins.
__global__ __launch_bounds__(256) void k_hist2(const int* __restrict__ src, const int* __restrict__ dst,
                        int* __restrict__ outdeg, int* __restrict__ indeg) {
    __shared__ unsigned lh[12500];   // 25000 nodes, 2 per word
    int chunk = blockIdx.x, r = blockIdx.y;
    int which = blockIdx.z >> 1, half = blockIdx.z & 1;
    const int* idx = (which ? dst : src) + (size_t)r * EE;
    int* deg = (which ? indeg : outdeg) + (size_t)r * NN;
    for (int i = threadIdx.x; i < 12500; i += 256) lh[i] = 0;
    __syncthreads();
    int e0 = chunk * (EE / 4);
    int lo = half * 25000;
    for (int e = e0 + threadIdx.x; e < e0 + EE / 4; e += 256) {
        int n = idx[e] - lo;
        if ((unsigned)n < 25000u)
            atomicAdd(&lh[n >> 1], 1u << ((n & 1) * 16));
    }
    __syncthreads();
    for (int i = threadIdx.x; i < 12500; i += 256) {
        unsigned v = lh[i];
        unsigned c0 = v & 0xffffu, c1 = v >> 16;
        if (c0) atomicAdd(&deg[lo + i * 2], (int)c0);
        if (c1) atomicAdd(&deg[lo + i * 2 + 1], (int)c1);
    }
}

// ---------------- norms: in-place int degree -> float rsqrt ----------------
__global__ void k_norms(int* __restrict__ outdeg, int* __restrict__ indeg) {
    int i = blockIdx.x * blockDim.x + threadIdx.x;
    if (i >= RR * NN) return;
    int od = outdeg[i];
    int id = indeg[i];
    ((float*)outdeg)[i] = od > 0 ? rsqrtf((float)od) : 0.f;
    ((float*)indeg)[i]  = id > 0 ? rsqrtf((float)id) : 0.f;
}

// ---------------- parallel scan: phase A (per-block sums) ----------------
__global__ void k_scanA(const int* __restrict__ indeg, int* __restrict__ bsum) {
    int r = blockIdx.y;
    int i = blockIdx.x * 256 + threadIdx.x;
    int v = (i < NN) ? indeg[(size_t)r * NN + i] : 0;
    #pragma unroll
    for (int d = 32; d > 0; d >>= 1) v += __shfl_down(v, d, 64);
    __shared__ int ws4[4];
    if ((threadIdx.x & 63) == 0) ws4[threadIdx.x >> 6] = v;
    __syncthreads();
    if (threadIdx.x == 0) bsum[r * SCB + blockIdx.x] = ws4[0] + ws4[1] + ws4[2] + ws4[3];
}

// ---------------- phase B: exclusive scan of SCB block sums per relation ----------------
__global__ void k_scanB(int* __restrict__ bsum, int* __restrict__ offs) {
    int r = blockIdx.x;
    int t = threadIdx.x;
    int v = (t < SCB) ? bsum[r * SCB + t] : 0;
    int lane = t & 63, wid = t >> 6;
    int sv = v;
    #pragma unroll
    for (int d = 1; d < 64; d <<= 1) {
        int u = __shfl_up(sv, d, 64);
        if (lane >= d) sv += u;
    }
    __shared__ int wsum[4];
    if (lane == 63) wsum[wid] = sv;
    __syncthreads();
    int add = 0;
    for (int x = 0; x < wid; x++) add += wsum[x];
    int incl = sv + add;
    if (t < SCB) bsum[r * SCB + t] = incl - v;
    if (t == 255) offs[(size_t)r * (NN + 1) + NN] = incl;  // grand total
}

// ---------------- phase C: intra-block exclusive scan + base ----------------
__global__ void k_scanC(const int* __restrict__ indeg, const int* __restrict__ bsum,
                        int* __restrict__ offs) {
    int r = blockIdx.y;
    int i = blockIdx.x * 256 + threadIdx.x;
    int v = (i < NN) ? indeg[(size_t)r * NN + i] : 0;
    int lane = threadIdx.x & 63, wid = threadIdx.x >> 6;
    int sv = v;
    #pragma unroll
    for (int d = 1; d < 64; d <<= 1) {
        int u = __shfl_up(sv, d, 64);
        if (lane >= d) sv += u;
    }
    __shared__ int wsum[4];
    if (lane == 63) wsum[wid] = sv;
    __syncthreads();
    int add = bsum[r * SCB + blockIdx.x];
    for (int x = 0; x < wid; x++) add += wsum[x];
    if (i < NN) offs[(size_t)r * (NN + 1) + i] = sv - v + add;
}

// ---------------- fill CSR ----------------
__global__ void k_fill(const int* __restrict__ src, const int* __restrict__ dst,
                       const int* __restrict__ offs, int* __restrict__ cursor,
                       int* __restrict__ csr) {
    int i = blockIdx.x * blockDim.x + threadIdx.x;
    if (i >= RR * EE) return;
    int r = i / EE;
    int d = dst[i];
    int pos = offs[r * (NN + 1) + d] + atomicAdd(&cursor[r * NN + d], 1);
    csr[(size_t)r * EE + pos] = src[i];
}

// ---------------- bias sums over relations ----------------
__global__ void k_bsum(const float* __restrict__ b2a, const float* __restrict__ b2b,
                       const float* __restrict__ b3a, const float* __restrict__ b3b,
                       float* __restrict__ bs) {
    int j = threadIdx.x;  // 256
    float s = 0.f;
    for (int r = 0; r < RR; r++) s += b2a[r * 256 + j];
    bs[j] = s;
    if (j < 128) {
        s = 0.f;
        for (int r = 0; r < RR; r++) s += b2b[r * 128 + j];
        bs[256 + j] = s;
    }
    s = 0.f;
    for (int r = 0; r < RR; r++) s += b3a[r * 256 + j];
    bs[512 + j] = s;
    if (j < 128) {
        s = 0.f;
        for (int r = 0; r < RR; r++) s += b3b[r * 128 + j];
        bs[768 + j] = s;
    }
}

// ---------------- fp32 -> bf16 elementwise cast ----------------
__global__ void k_cast(const float* __restrict__ x, unsigned short* __restrict__ y, int total) {
    int i = blockIdx.x * blockDim.x + threadIdx.x;
    if (i < total) y[i] = f2bf(x[i]);
}

// ---------------- weights: W[R,K0,Nout] -> WT[Nout][R*Kpad] bf16 ----------------
__global__ void k_wt(const float* __restrict__ W, unsigned short* __restrict__ WT,
                     int K0, int Kpad, int Nout) {
    int i = blockIdx.x * blockDim.x + threadIdx.x;
    int total = Nout * RR * Kpad;
    if (i >= total) return;
    int n = i / (RR * Kpad);
    int rem = i - n * (RR * Kpad);
    int r = rem / Kpad;
    int k = rem - r * Kpad;
    float v = (k < K0) ? W[((size_t)r * K0 + k) * Nout + n] : 0.f;
    WT[i] = f2bf(v);
}

// ---------------- aggregation: TPN threads per node, 256/TPN nodes per block ----------------
template<int TPN>
__global__ void k_agg(const unsigned short* __restrict__ xb, int xstride, int din4, int nch,
                      const int* __restrict__ csr, const int* __restrict__ offs,
                      const float* __restrict__ ns, const float* __restrict__ nd,
                      int rbase, int nbase, unsigned short* __restrict__ Y,
                      int Kpad, int ystride) {
    constexpr int NPB = 256 / TPN;
    int sub = threadIdx.x / TPN;
    int j = threadIdx.x % TPN;
    int bn = blockIdx.x * NPB + sub;          // row within chunk
    int n = nbase + bn;
    int r = rbase + blockIdx.y;
    if (j >= nch) return;
    int o0 = offs[r * (NN + 1) + n];
    int o1 = offs[r * (NN + 1) + n + 1];
    float ndv = nd[(size_t)r * NN + n];
    const int* cs = csr + (size_t)r * EE;
    float a0 = 0.f, a1 = 0.f, a2 = 0.f, a3 = 0.f;
    if (j < din4) {
        for (int e = o0; e < o1; e++) {
            int s = cs[e];
            float w = ns[(size_t)r * NN + s];
            ushort4 v = *(const ushort4*)(xb + (size_t)s * xstride + j * 4);
            a0 += w * bf2f(v.x); a1 += w * bf2f(v.y);
            a2 += w * bf2f(v.z); a3 += w * bf2f(v.w);
        }
    }
    ushort4 o;
    o.x = f2bf(a0 * ndv); o.y = f2bf(a1 * ndv);
    o.z = f2bf(a2 * ndv); o.w = f2bf(a3 * ndv);
    *(ushort4*)(Y + (size_t)bn * ystride + (size_t)blockIdx.y * Kpad + j * 4) = o;
}

// ---------------- bf16 MFMA GEMM, async-LDS staged, XOR-swizzled ----------------
// Tile 128 x (TN*32). A [M x K] bf16 (lda), BT [Nout x K] bf16 (ldb).
// flags: 1=addbias, 2=accum(read Cin fp32), 4=relu, 8=out bf16 (else fp32)
template<int TN>
__global__ __launch_bounds__(256) void k_gemm_bf(
        const unsigned short* __restrict__ A, int lda,
        const unsigned short* __restrict__ BT, int ldb,
        const float* __restrict__ bias,
        const float* __restrict__ Cin, int ldcin,
        void* __restrict__ Cout, int ldc,
        int M, int K, int flags) {
    constexpr int BN = TN * 32;
    __shared__ unsigned short As[128 * 64];
    __shared__ unsigned short Bs[BN * 64];
    int m0 = blockIdx.x * 128;
    int n0 = blockIdx.y * BN;
    int t = threadIdx.x;
    int w = t >> 6, l = t & 63;
    int qm = (w >> 1) * 64, qn = (w & 1) * (TN * 16);
    int lr = l & 15, lg = l >> 4;
    int lrow = l >> 3;            // row within 8-row segment
    int lch  = (l & 7) ^ lrow;    // swizzled source chunk (8 bf16 each)

    floatx4 acc[4][TN];
    #pragma unroll
    for (int a = 0; a < 4; a++)
        #pragma unroll
        for (int b = 0; b < TN; b++)
            acc[a][b] = (floatx4){0.f, 0.f, 0.f, 0.f};

    for (int k0 = 0; k0 < K; k0 += 64) {
        #pragma unroll
        for (int j = 0; j < 4; j++) {
            int seg = w * 4 + j;              // 16 segments x 8 rows = 128 rows
            int gr = m0 + seg * 8 + lrow; if (gr > M - 1) gr = M - 1;
            gload_lds16(A + (size_t)gr * lda + k0 + lch * 8, &As[seg * 512]);
        }
        #pragma unroll
        for (int j = 0; j < TN; j++) {
            int seg = w * TN + j;             // BN/8 segments
            int row = n0 + seg * 8 + lrow;
            gload_lds16(BT + (size_t)row * ldb + k0 + lch * 8, &Bs[seg * 512]);
        }
        __syncthreads();
        #pragma unroll
        for (int ks = 0; ks < 2; ks++) {
            int slot = ((ks * 4 + lg) ^ (lr & 7)) * 8;
            short8 af[4], bf[TN];
            #pragma unroll
            for (int i = 0; i < 4; i++)
                af[i] = *(const short8*)&As[(qm + i * 16 + lr) * 64 + slot];
            #pragma unroll
            for (int i = 0; i < TN; i++)
                bf[i] = *(const short8*)&Bs[(qn + i * 16 + lr) * 64 + slot];
            #pragma unroll
            for (int tm = 0; tm < 4; tm++)
                #pragma unroll
                for (int tn = 0; tn < TN; tn++)
                    acc[tm][tn] = __builtin_amdgcn_mfma_f32_16x16x32_bf16(
                        af[tm], bf[tn], acc[tm][tn], 0, 0, 0);
        }
        __syncthreads();
    }

    int addbias = flags & 1, accum = flags & 2, relu = flags & 4, outbf = flags & 8;
    #pragma unroll
    for (int tm = 0; tm < 4; tm++) {
        int rbase = m0 + qm + tm * 16 + lg * 4;
        #pragma unroll
        for (int reg = 0; reg < 4; reg++) {
            int row = rbase + reg;
            if (row >= M) continue;
            #pragma unroll
            for (int tn = 0; tn < TN; tn++) {
                int col = n0 + qn + tn * 16 + lr;
                float v = acc[tm][tn][reg];
                if (addbias) v += bias[col];
                if (accum) v += Cin[(size_t)row * ldcin + col];
                if (relu) v = fmaxf(v, 0.f);
                if (outbf) ((unsigned short*)Cout)[(size_t)row * ldc + col] = f2bf(v);
                else       ((float*)Cout)[(size_t)row * ldc + col] = v;
            }
        }
    }
}

// ---------------- fused decoder weights ----------------
__global__ void k_mcat(const float* __restrict__ Wp1, const float* __restrict__ Wp2,
                       const float* __restrict__ bp1, const float* __restrict__ bp2,
                       float* __restrict__ Mcat, float* __restrict__ cvec) {
    int t = blockIdx.x * blockDim.x + threadIdx.x;
    if (t < 4096) {
        int i = t >> 4, j = t & 15;
        int half = j >> 3, jj = j & 7;
        const float* wrow = Wp1 + (size_t)(half * 256 + i) * 256;
        float s = 0.f;
        for (int k = 0; k < 256; k++) s += wrow[k] * Wp2[k * 8 + jj];
        Mcat[i * 16 + j] = s;
    } else if (t < 4096 + 8) {
        int j = t - 4096;
        float s = bp2[j];
        for (int k = 0; k < 256; k++) s += bp1[k] * Wp2[k * 8 + j];
        cvec[j] = s;
    }
}

// ---------------- AB = feat @ Mcat  [N x 16] (float4 loads) ----------------
__global__ void k_ab(const float* __restrict__ feat, const float* __restrict__ Mcat,
                     float* __restrict__ AB) {
    __shared__ float Ms[4096];
    int t = threadIdx.x;
    for (int i = t; i < 4096; i += 256) Ms[i] = Mcat[i];
    __syncthreads();
    int n = blockIdx.x * 16 + (t >> 4);
    int c = t & 15;
    const float4* fr = (const float4*)(feat + (size_t)n * 256);
    float s = 0.f;
    #pragma unroll 8
    for (int k4 = 0; k4 < 64; k4++) {
        float4 v = fr[k4];
        s += v.x * Ms[(k4 * 4 + 0) * 16 + c] + v.y * Ms[(k4 * 4 + 1) * 16 + c]
           + v.z * Ms[(k4 * 4 + 2) * 16 + c] + v.w * Ms[(k4 * 4 + 3) * 16 + c];
    }
    AB[(size_t)n * 16 + c] = s;
}

// ---------------- per-edge decoder ----------------
__global__ void k_dec(const int* __restrict__ dsrc, const int* __restrict__ ddst,
                      const float* __restrict__ AB, const float* __restrict__ cvec,
                      float* __restrict__ out) {
    int i = blockIdx.x * blockDim.x + threadIdx.x;
    if (i >= EDD * 8) return;
    int e = i >> 3, k = i & 7;
    out[i] = AB[dsrc[e] * 16 + k] + AB[ddst[e] * 16 + 8 + k] + cvec[k];
}

extern "C" void kernel_launch(void* const* d_in, const int* in_sizes, int n_in,
                              void* d_out, int out_size, void* d_ws, size_t ws_size,
                              hipStream_t stream) {
    const float* x2  = (const float*)d_in[0];
    const float* x3  = (const float*)d_in[1];
    const int*   src = (const int*)d_in[2];
    const int*   dst = (const int*)d_in[3];
    const int*   dsrc = (const int*)d_in[4];
    const int*   ddst = (const int*)d_in[5];
    const float* W2a = (const float*)d_in[6];
    const float* b2a = (const float*)d_in[7];
    const float* W2b = (const float*)d_in[8];
    const float* b2b = (const float*)d_in[9];
    const float* W3a = (const float*)d_in[10];
    const float* b3a = (const float*)d_in[11];
    const float* W3b = (const float*)d_in[12];
    const float* b3b = (const float*)d_in[13];
    const float* Wp1 = (const float*)d_in[14];
    const float* bp1 = (const float*)d_in[15];
    const float* Wp2 = (const float*)d_in[16];
    const float* bp2 = (const float*)d_in[17];
    float* out = (float*)d_out;

    // ---- workspace layout (~181.8 MB) ----
    char* ws = (char*)d_ws;
    size_t off = 0;
    auto alloc = [&](size_t nbytes) {
        char* p = ws + off;
        off += nbytes;
        off = (off + 255) & ~(size_t)255;
        return p;
    };
    float* ns   = (float*)alloc((size_t)RR * NN * 4);        // aliases outdeg
    float* nd   = (float*)alloc((size_t)RR * NN * 4);        // aliases indeg
    int*   offs = (int*)alloc((size_t)RR * (NN + 1) * 4);
    int*   csr  = (int*)alloc((size_t)RR * EE * 4);
    unsigned short* XH   = (unsigned short*)alloc((size_t)NN * 300 * 2);  // x2b then x3b
    unsigned short* hbuf = (unsigned short*)alloc((size_t)NN * 256 * 2);  // layer-a out; AB aliases
    unsigned short* WT2a = (unsigned short*)alloc((size_t)256 * 2048 * 2);
    unsigned short* WT2b = (unsigned short*)alloc((size_t)128 * 2048 * 2);
    unsigned short* WT3a = (unsigned short*)alloc((size_t)256 * 2432 * 2);
    unsigned short* WT3b = (unsigned short*)alloc((size_t)128 * 2048 * 2);
    unsigned short* Y    = (unsigned short*)alloc((size_t)12500 * 2432 * 2);  // cursor aliases head
    float* feat  = (float*)alloc((size_t)NN * 256 * 4);
    float* bsums = (float*)alloc(1024 * 4);
    float* Mcat  = (float*)alloc(4096 * 4);
    float* cvec  = (float*)alloc(64 * 4);
    int*   bsum  = (int*)alloc((size_t)RR * SCB * 4);

    int*   outdeg = (int*)ns;
    int*   indeg  = (int*)nd;
    int*   cursor = (int*)Y;       // only live during k_fill (before any Y use)
    float* AB     = (float*)hbuf;  // only live after last hbuf read

    // ---- graph prep ----
    hipMemsetAsync(outdeg, 0, (size_t)RR * NN * 4, stream);
    hipMemsetAsync(indeg,  0, (size_t)RR * NN * 4, stream);
    hipMemsetAsync(cursor, 0, (size_t)RR * NN * 4, stream);

    k_hist2<<<dim3(4, RR, 4), 256, 0, stream>>>(src, dst, outdeg, indeg);
    k_scanA<<<dim3(SCB, RR), 256, 0, stream>>>(indeg, bsum);
    k_scanB<<<RR, 256, 0, stream>>>(bsum, offs);
    k_scanC<<<dim3(SCB, RR), 256, 0, stream>>>(indeg, bsum, offs);
    k_norms<<<(RR * NN + 255) / 256, 256, 0, stream>>>(outdeg, indeg);
    int histBlocks = (RR * EE + 255) / 256;
    k_fill<<<histBlocks, 256, 0, stream>>>(src, dst, offs, cursor, csr);
    k_bsum<<<1, 256, 0, stream>>>(b2a, b2b, b3a, b3b, bsums);
    k_mcat<<<17, 256, 0, stream>>>(Wp1, Wp2, bp1, bp2, Mcat, cvec);

    k_cast<<<(NN * 256 + 255) / 256, 256, 0, stream>>>(x2, XH, NN * 256);
    k_wt<<<(256 * RR * 256 + 255) / 256, 256, 0, stream>>>(W2a, WT2a, 256, 256, 256);
    k_wt<<<(128 * RR * 256 + 255) / 256, 256, 0, stream>>>(W2b, WT2b, 256, 256, 128);
    k_wt<<<(256 * RR * 304 + 255) / 256, 256, 0, stream>>>(W3a, WT3a, 300, 304, 256);
    k_wt<<<(128 * RR * 256 + 255) / 256, 256, 0, stream>>>(W3b, WT3b, 256, 256, 128);

    const int CH = 12500;                  // node chunk (4 chunks)
    dim3 gChunkA((CH + 127) / 128, 4);     // layer-a GEMM: BN=64, Nout=256
    dim3 gChunkB((CH + 127) / 128, 2);     // layer-b GEMM: BN=64, Nout=128

    // ---- layer 2a: hbuf = relu(sum_r agg_r(x2b) @ W2a_r + b) ----
    for (int c = 0; c < 4; c++) {
        int nb = c * CH;
        k_agg<64><<<dim3(CH / 4, 8), 256, 0, stream>>>(XH, 256, 64, 64, csr, offs, ns, nd,
                                                       0, nb, Y, 256, 2048);
        k_gemm_bf<2><<<gChunkA, 256, 0, stream>>>(Y, 2048, WT2a, 2048, bsums + 0,
                                                  feat, 256, (void*)(hbuf + (size_t)nb * 256), 256,
                                                  CH, 2048, 1 | 4 | 8);
    }
    // ---- layer 2b: feat[:, :128] (node-chunked, single K=2048 GEMM per chunk) ----
    for (int c = 0; c < 4; c++) {
        int nb = c * CH;
        k_agg<64><<<dim3(CH / 4, 8), 256, 0, stream>>>(hbuf, 256, 64, 64, csr, offs, ns, nd,
                                                       0, nb, Y, 256, 2048);
        k_gemm_bf<2><<<gChunkB, 256, 0, stream>>>(Y, 2048, WT2b, 2048, bsums + 256,
                                                  feat, 256, (void*)(feat + (size_t)nb * 256), 256,
                                                  CH, 2048, 1);
    }
    // ---- layer 3a (x3: din 300) ----
    k_cast<<<(NN * 300 + 255) / 256, 256, 0, stream>>>(x3, XH, NN * 300);
    for (int c = 0; c < 4; c++) {
        int nb = c * CH;
        k_agg<128><<<dim3(CH / 2, 8), 256, 0, stream>>>(XH, 300, 75, 76, csr, offs, ns, nd,
                                                        0, nb, Y, 304, 2432);
        k_gemm_bf<2><<<gChunkA, 256, 0, stream>>>(Y, 2432, WT3a, 2432, bsums + 512,
                                                  feat, 256, (void*)(hbuf + (size_t)nb * 256), 256,
                                                  CH, 2432, 1 | 4 | 8);
    }
    // ---- layer 3b: feat[:, 128:] ----
    for (int c = 0; c < 4; c++) {
        int nb = c * CH;
        k_agg<64><<<dim3(CH / 4, 8), 256, 0, stream>>>(hbuf, 256, 64, 64, csr, offs, ns, nd,
                                                       0, nb, Y, 256, 2048);
        k_gemm_bf<2><<<gChunkB, 256, 0, stream>>>(Y, 2048, WT3b, 2048, bsums + 768,
                                                  feat, 256, (void*)(feat + (size_t)nb * 256 + 128), 256,
                                                  CH, 2048, 1);
    }

    // ---- decoder ----
    k_ab<<<NN / 16, 256, 0, stream>>>(feat, Mcat, AB);
    k_dec<<<(EDD * 8 + 255) / 256, 256, 0, stream>>>(dsrc, ddst, AB, cvec, out);
}

// Round 6
// 2066.458 us; speedup vs baseline: 1.0772x; 1.0772x over previous
//
#include <hip/hip_runtime.h>
#include <hip/hip_bf16.h>

#define NN 50000
#define RR 8
#define EE 200000
#define EDD 400000
#define SCB 196   // ceil(NN/256) scan blocks

typedef __attribute__((ext_vector_type(8))) short short8;
typedef __attribute__((ext_vector_type(4))) float floatx4;

static __device__ __forceinline__ unsigned short f2bf(float f) {
    union { float f; unsigned u; } v; v.f = f;
    unsigned r = v.u + 0x7fff + ((v.u >> 16) & 1);
    return (unsigned short)(r >> 16);
}
static __device__ __forceinline__ float bf2f(unsigned short h) {
    union { unsigned u; float f; } v; v.u = ((unsigned)h) << 16;
    return v.f;
}
// async global->LDS, 16B per lane; LDS dest = uniform base + lane*16
static __device__ __forceinline__ void gload_lds16(const unsigned short* g, unsigned short* l) {
    __builtin_amdgcn_global_load_lds(
        (const __attribute__((address_space(1))) void*)g,
        (__attribute__((address_space(3))) void*)l,
        16, 0, 0);
}

// ---------------- LDS-privatized degree histogram ----------------
// grid (8 edge-chunks, RR, 4: z = which*2 + node-half). 16-bit packed LDS bins.
__global__ __launch_bounds__(256) void k_hist2(const int* __restrict__ src, const int* __restrict__ dst,
                        int* __restrict__ outdeg, int* __restrict__ indeg) {
    __shared__ unsigned lh[12500];   // 25000 nodes, 2 per word
    int chunk = blockIdx.x, r = blockIdx.y;
    int which = blockIdx.z >> 1, half = blockIdx.z & 1;
    const int* idx = (which ? dst : src) + (size_t)r * EE;
    int* deg = (which ? indeg : outdeg) + (size_t)r * NN;
    for (int i = threadIdx.x; i < 12500; i += 256) lh[i] = 0;
    __syncthreads();
    int e0 = chunk * (EE / 8);
    int lo = half * 25000;
    for (int e = e0 + threadIdx.x; e < e0 + EE / 8; e += 256) {
        int n = idx[e] - lo;
        if ((unsigned)n < 25000u)
            atomicAdd(&lh[n >> 1], 1u << ((n & 1) * 16));
    }
    __syncthreads();
    for (int i = threadIdx.x; i < 12500; i += 256) {
        unsigned v = lh[i];
        unsigned c0 = v & 0xffffu, c1 = v >> 16;
        if (c0) atomicAdd(&deg[lo + i * 2], (int)c0);
        if (c1) atomicAdd(&deg[lo + i * 2 + 1], (int)c1);
    }
}

// ---------------- norms: in-place int degree -> float rsqrt ----------------
__global__ void k_norms(int* __restrict__ outdeg, int* __restrict__ indeg) {
    int i = blockIdx.x * blockDim.x + threadIdx.x;
    if (i >= RR * NN) return;
    int od = outdeg[i];
    int id = indeg[i];
    ((float*)outdeg)[i] = od > 0 ? rsqrtf((float)od) : 0.f;
    ((float*)indeg)[i]  = id > 0 ? rsqrtf((float)id) : 0.f;
}

// ---------------- parallel scan: phase A (per-block sums) ----------------
__global__ void k_scanA(const int* __restrict__ indeg, int* __restrict__ bsum) {
    int r = blockIdx.y;
    int i = blockIdx.x * 256 + threadIdx.x;
    int v = (i < NN) ? indeg[(size_t)r * NN + i] : 0;
    #pragma unroll
    for (int d = 32; d > 0; d >>= 1) v += __shfl_down(v, d, 64);
    __shared__ int ws4[4];
    if ((threadIdx.x & 63) == 0) ws4[threadIdx.x >> 6] = v;
    __syncthreads();
    if (threadIdx.x == 0) bsum[r * SCB + blockIdx.x] = ws4[0] + ws4[1] + ws4[2] + ws4[3];
}

// ---------------- phase B: exclusive scan of SCB block sums per relation ----------------
__global__ void k_scanB(int* __restrict__ bsum, int* __restrict__ offs) {
    int r = blockIdx.x;
    int t = threadIdx.x;
    int v = (t < SCB) ? bsum[r * SCB + t] : 0;
    int lane = t & 63, wid = t >> 6;
    int sv = v;
    #pragma unroll
    for (int d = 1; d < 64; d <<= 1) {
        int u = __shfl_up(sv, d, 64);
        if (lane >= d) sv += u;
    }
    __shared__ int wsum[4];
    if (lane == 63) wsum[wid] = sv;
    __syncthreads();
    int add = 0;
    for (int x = 0; x < wid; x++) add += wsum[x];
    int incl = sv + add;
    if (t < SCB) bsum[r * SCB + t] = incl - v;
    if (t == 255) offs[(size_t)r * (NN + 1) + NN] = incl;  // grand total
}

// ---------------- phase C: intra-block exclusive scan + base ----------------
__global__ void k_scanC(const int* __restrict__ indeg, const int* __restrict__ bsum,
                        int* __restrict__ offs) {
    int r = blockIdx.y;
    int i = blockIdx.x * 256 + threadIdx.x;
    int v = (i < NN) ? indeg[(size_t)r * NN + i] : 0;
    int lane = threadIdx.x & 63, wid = threadIdx.x >> 6;
    int sv = v;
    #pragma unroll
    for (int d = 1; d < 64; d <<= 1) {
        int u = __shfl_up(sv, d, 64);
        if (lane >= d) sv += u;
    }
    __shared__ int wsum[4];
    if (lane == 63) wsum[wid] = sv;
    __syncthreads();
    int add = bsum[r * SCB + blockIdx.x];
    for (int x = 0; x < wid; x++) add += wsum[x];
    if (i < NN) offs[(size_t)r * (NN + 1) + i] = sv - v + add;
}

// ---------------- fill CSR with fused src-norm weight: (src, ns[r][src]) ----------------
__global__ void k_fillw(const int* __restrict__ src, const int* __restrict__ dst,
                        const int* __restrict__ offs, const float* __restrict__ ns,
                        int* __restrict__ cursor, int2* __restrict__ csrw) {
    int i = blockIdx.x * blockDim.x + threadIdx.x;
    if (i >= RR * EE) return;
    int r = i / EE;
    int s = src[i], d = dst[i];
    int pos = offs[r * (NN + 1) + d] + atomicAdd(&cursor[r * NN + d], 1);
    int2 v;
    v.x = s;
    v.y = __float_as_int(ns[(size_t)r * NN + s]);
    csrw[(size_t)r * EE + pos] = v;
}

// ---------------- bias sums over relations ----------------
__global__ void k_bsum(const float* __restrict__ b2a, const float* __restrict__ b2b,
                       const float* __restrict__ b3a, const float* __restrict__ b3b,
                       float* __restrict__ bs) {
    int j = threadIdx.x;  // 256
    float s = 0.f;
    for (int r = 0; r < RR; r++) s += b2a[r * 256 + j];
    bs[j] = s;
    if (j < 128) {
        s = 0.f;
        for (int r = 0; r < RR; r++) s += b2b[r * 128 + j];
        bs[256 + j] = s;
    }
    s = 0.f;
    for (int r = 0; r < RR; r++) s += b3a[r * 256 + j];
    bs[512 + j] = s;
    if (j < 128) {
        s = 0.f;
        for (int r = 0; r < RR; r++) s += b3b[r * 128 + j];
        bs[768 + j] = s;
    }
}

// ---------------- fp32 -> bf16 elementwise cast ----------------
__global__ void k_cast(const float* __restrict__ x, unsigned short* __restrict__ y, int total) {
    int i = blockIdx.x * blockDim.x + threadIdx.x;
    if (i < total) y[i] = f2bf(x[i]);
}

// ---------------- weights: W[R,K0,Nout] -> WT[Nout][R*Kpad] bf16 ----------------
__global__ void k_wt(const float* __restrict__ W, unsigned short* __restrict__ WT,
                     int K0, int Kpad, int Nout) {
    int i = blockIdx.x * blockDim.x + threadIdx.x;
    int total = Nout * RR * Kpad;
    if (i >= total) return;
    int n = i / (RR * Kpad);
    int rem = i - n * (RR * Kpad);
    int r = rem / Kpad;
    int k = rem - r * Kpad;
    float v = (k < K0) ? W[((size_t)r * K0 + k) * Nout + n] : 0.f;
    WT[i] = f2bf(v);
}

// ---------------- aggregation: 4-deep batched gather, fused edge weights ----------------
// TPN threads per node, 256/TPN nodes per block.
template<int TPN>
__global__ void k_agg(const unsigned short* __restrict__ xb, int xstride, int din4, int nch,
                      const int2* __restrict__ csrw, const int* __restrict__ offs,
                      const float* __restrict__ nd,
                      int rbase, int nbase, unsigned short* __restrict__ Y,
                      int Kpad, int ystride) {
    constexpr int NPB = 256 / TPN;
    int sub = threadIdx.x / TPN;
    int j = threadIdx.x % TPN;
    int bn = blockIdx.x * NPB + sub;          // row within chunk
    int n = nbase + bn;
    int r = rbase + blockIdx.y;
    int o0 = offs[r * (NN + 1) + n];
    int o1 = offs[r * (NN + 1) + n + 1];
    float ndv = nd[(size_t)r * NN + n];
    const int2* cs = csrw + (size_t)r * EE;
    int jj = (j < din4) ? j : (din4 - 1);     // pad lanes duplicate last chunk (coalesced)
    float sc = (j < din4) ? ndv : 0.f;        // pad lanes write zeros
    float a0 = 0.f, a1 = 0.f, a2 = 0.f, a3 = 0.f;
    for (int e0 = o0; e0 < o1; e0 += 4) {
        int2 ew[4];
        float wq[4];
        ushort4 vq[4];
        #pragma unroll
        for (int q = 0; q < 4; q++) {
            int e = e0 + q;
            ew[q] = cs[e < o1 ? e : o0];
        }
        #pragma unroll
        for (int q = 0; q < 4; q++) {
            wq[q] = (e0 + q < o1) ? __int_as_float(ew[q].y) : 0.f;
            vq[q] = *(const ushort4*)(xb + (size_t)(unsigned)ew[q].x * xstride + jj * 4);
        }
        #pragma unroll
        for (int q = 0; q < 4; q++) {
            a0 += wq[q] * bf2f(vq[q].x);
            a1 += wq[q] * bf2f(vq[q].y);
            a2 += wq[q] * bf2f(vq[q].z);
            a3 += wq[q] * bf2f(vq[q].w);
        }
    }
    if (j < nch) {
        ushort4 o;
        o.x = f2bf(a0 * sc); o.y = f2bf(a1 * sc);
        o.z = f2bf(a2 * sc); o.w = f2bf(a3 * sc);
        *(ushort4*)(Y + (size_t)bn * ystride + (size_t)blockIdx.y * Kpad + j * 4) = o;
    }
}

// ---------------- bf16 MFMA GEMM, async-LDS staged, XOR-swizzled ----------------
// Tile 128 x (TN*32). A [M x K] bf16 (lda), BT [Nout x K] bf16 (ldb).
// flags: 1=addbias, 2=accum(read Cin fp32), 4=relu, 8=out bf16 (else fp32)
template<int TN>
__global__ __launch_bounds__(256) void k_gemm_bf(
        const unsigned short* __restrict__ A, int lda,
        const unsigned short* __restrict__ BT, int ldb,
        const float* __restrict__ bias,
        const float* __restrict__ Cin, int ldcin,
        void* __restrict__ Cout, int ldc,
        int M, int K, int flags) {
    constexpr int BN = TN * 32;
    __shared__ unsigned short As[128 * 64];
    __shared__ unsigned short Bs[BN * 64];
    int m0 = blockIdx.x * 128;
    int n0 = blockIdx.y * BN;
    int t = threadIdx.x;
    int w = t >> 6, l = t & 63;
    int qm = (w >> 1) * 64, qn = (w & 1) * (TN * 16);
    int lr = l & 15, lg = l >> 4;
    int lrow = l >> 3;            // row within 8-row segment
    int lch  = (l & 7) ^ lrow;    // swizzled source chunk (8 bf16 each)

    floatx4 acc[4][TN];
    #pragma unroll
    for (int a = 0; a < 4; a++)
        #pragma unroll
        for (int b = 0; b < TN; b++)
            acc[a][b] = (floatx4){0.f, 0.f, 0.f, 0.f};

    for (int k0 = 0; k0 < K; k0 += 64) {
        #pragma unroll
        for (int j = 0; j < 4; j++) {
            int seg = w * 4 + j;              // 16 segments x 8 rows = 128 rows
            int gr = m0 + seg * 8 + lrow; if (gr > M - 1) gr = M - 1;
            gload_lds16(A + (size_t)gr * lda + k0 + lch * 8, &As[seg * 512]);
        }
        #pragma unroll
        for (int j = 0; j < TN; j++) {
            int seg = w * TN + j;             // BN/8 segments
            int row = n0 + seg * 8 + lrow;
            gload_lds16(BT + (size_t)row * ldb + k0 + lch * 8, &Bs[seg * 512]);
        }
        __syncthreads();
        #pragma unroll
        for (int ks = 0; ks < 2; ks++) {
            int slot = ((ks * 4 + lg) ^ (lr & 7)) * 8;
            short8 af[4], bf[TN];
            #pragma unroll
            for (int i = 0; i < 4; i++)
                af[i] = *(const short8*)&As[(qm + i * 16 + lr) * 64 + slot];
            #pragma unroll
            for (int i = 0; i < TN; i++)
                bf[i] = *(const short8*)&Bs[(qn + i * 16 + lr) * 64 + slot];
            #pragma unroll
            for (int tm = 0; tm < 4; tm++)
                #pragma unroll
                for (int tn = 0; tn < TN; tn++)
                    acc[tm][tn] = __builtin_amdgcn_mfma_f32_16x16x32_bf16(
                        af[tm], bf[tn], acc[tm][tn], 0, 0, 0);
        }
        __syncthreads();
    }

    int addbias = flags & 1, accum = flags & 2, relu = flags & 4, outbf = flags & 8;
    #pragma unroll
    for (int tm = 0; tm < 4; tm++) {
        int rbase = m0 + qm + tm * 16 + lg * 4;
        #pragma unroll
        for (int reg = 0; reg < 4; reg++) {
            int row = rbase + reg;
            if (row >= M) continue;
            #pragma unroll
            for (int tn = 0; tn < TN; tn++) {
                int col = n0 + qn + tn * 16 + lr;
                float v = acc[tm][tn][reg];
                if (addbias) v += bias[col];
                if (accum) v += Cin[(size_t)row * ldcin + col];
                if (relu) v = fmaxf(v, 0.f);
                if (outbf) ((unsigned short*)Cout)[(size_t)row * ldc + col] = f2bf(v);
                else       ((float*)Cout)[(size_t)row * ldc + col] = v;
            }
        }
    }
}

// ---------------- fused decoder weights ----------------
__global__ void k_mcat(const float* __restrict__ Wp1, const float* __restrict__ Wp2,
                       const float* __restrict__ bp1, const float* __restrict__ bp2,
                       float* __restrict__ Mcat, float* __restrict__ cvec) {
    int t = blockIdx.x * blockDim.x + threadIdx.x;
    if (t < 4096) {
        int i = t >> 4, j = t & 15;
        int half = j >> 3, jj = j & 7;
        const float* wrow = Wp1 + (size_t)(half * 256 + i) * 256;
        float s = 0.f;
        for (int k = 0; k < 256; k++) s += wrow[k] * Wp2[k * 8 + jj];
        Mcat[i * 16 + j] = s;
    } else if (t < 4096 + 8) {
        int j = t - 4096;
        float s = bp2[j];
        for (int k = 0; k < 256; k++) s += bp1[k] * Wp2[k * 8 + j];
        cvec[j] = s;
    }
}

// ---------------- AB = feat @ Mcat  [N x 16] (float4 loads) ----------------
__global__ void k_ab(const float* __restrict__ feat, const float* __restrict__ Mcat,
                     float* __restrict__ AB) {
    __shared__ float Ms[4096];
    int t = threadIdx.x;
    for (int i = t; i < 4096; i += 256) Ms[i] = Mcat[i];
    __syncthreads();
    int n = blockIdx.x * 16 + (t >> 4);
    int c = t & 15;
    const float4* fr = (const float4*)(feat + (size_t)n * 256);
    float s = 0.f;
    #pragma unroll 8
    for (int k4 = 0; k4 < 64; k4++) {
        float4 v = fr[k4];
        s += v.x * Ms[(k4 * 4 + 0) * 16 + c] + v.y * Ms[(k4 * 4 + 1) * 16 + c]
           + v.z * Ms[(k4 * 4 + 2) * 16 + c] + v.w * Ms[(k4 * 4 + 3) * 16 + c];
    }
    AB[(size_t)n * 16 + c] = s;
}

// ---------------- per-edge decoder ----------------
__global__ void k_dec(const int* __restrict__ dsrc, const int* __restrict__ ddst,
                      const float* __restrict__ AB, const float* __restrict__ cvec,
                      float* __restrict__ out) {
    int i = blockIdx.x * blockDim.x + threadIdx.x;
    if (i >= EDD * 8) return;
    int e = i >> 3, k = i & 7;
    out[i] = AB[dsrc[e] * 16 + k] + AB[ddst[e] * 16 + 8 + k] + cvec[k];
}

extern "C" void kernel_launch(void* const* d_in, const int* in_sizes, int n_in,
                              void* d_out, int out_size, void* d_ws, size_t ws_size,
                              hipStream_t stream) {
    const float* x2  = (const float*)d_in[0];
    const float* x3  = (const float*)d_in[1];
    const int*   src = (const int*)d_in[2];
    const int*   dst = (const int*)d_in[3];
    const int*   dsrc = (const int*)d_in[4];
    const int*   ddst = (const int*)d_in[5];
    const float* W2a = (const float*)d_in[6];
    const float* b2a = (const float*)d_in[7];
    const float* W2b = (const float*)d_in[8];
    const float* b2b = (const float*)d_in[9];
    const float* W3a = (const float*)d_in[10];
    const float* b3a = (const float*)d_in[11];
    const float* W3b = (const float*)d_in[12];
    const float* b3b = (const float*)d_in[13];
    const float* Wp1 = (const float*)d_in[14];
    const float* bp1 = (const float*)d_in[15];
    const float* Wp2 = (const float*)d_in[16];
    const float* bp2 = (const float*)d_in[17];
    float* out = (float*)d_out;

    // ---- workspace layout (~176 MB, < proven 182.4 MB bound) ----
    char* ws = (char*)d_ws;
    size_t off = 0;
    auto alloc = [&](size_t nbytes) {
        char* p = ws + off;
        off += nbytes;
        off = (off + 255) & ~(size_t)255;
        return p;
    };
    float* ns   = (float*)alloc((size_t)RR * NN * 4);        // aliases outdeg
    float* nd   = (float*)alloc((size_t)RR * NN * 4);        // aliases indeg
    int*   offs = (int*)alloc((size_t)RR * (NN + 1) * 4);
    int2*  csrw = (int2*)alloc((size_t)RR * EE * 8);
    unsigned short* XH   = (unsigned short*)alloc((size_t)NN * 300 * 2);  // x2b then x3b
    unsigned short* hbuf = (unsigned short*)alloc((size_t)NN * 256 * 2);  // layer-a out; AB aliases
    unsigned short* WT2a = (unsigned short*)alloc((size_t)256 * 2048 * 2);
    unsigned short* WT2b = (unsigned short*)alloc((size_t)128 * 2048 * 2);
    unsigned short* WT3a = (unsigned short*)alloc((size_t)256 * 2432 * 2);
    unsigned short* WT3b = (unsigned short*)alloc((size_t)128 * 2048 * 2);
    unsigned short* Y    = (unsigned short*)alloc((size_t)10000 * 2432 * 2);  // cursor aliases head
    float* feat  = (float*)alloc((size_t)NN * 256 * 4);
    float* bsums = (float*)alloc(1024 * 4);
    float* Mcat  = (float*)alloc(4096 * 4);
    float* cvec  = (float*)alloc(64 * 4);
    int*   bsum  = (int*)alloc((size_t)RR * SCB * 4);

    int*   outdeg = (int*)ns;
    int*   indeg  = (int*)nd;
    int*   cursor = (int*)Y;       // only live during k_fillw (before any Y use)
    float* AB     = (float*)hbuf;  // only live after last hbuf read

    // ---- graph prep ----
    hipMemsetAsync(outdeg, 0, (size_t)RR * NN * 4, stream);
    hipMemsetAsync(indeg,  0, (size_t)RR * NN * 4, stream);
    hipMemsetAsync(cursor, 0, (size_t)RR * NN * 4, stream);

    k_hist2<<<dim3(8, RR, 4), 256, 0, stream>>>(src, dst, outdeg, indeg);
    k_scanA<<<dim3(SCB, RR), 256, 0, stream>>>(indeg, bsum);
    k_scanB<<<RR, 256, 0, stream>>>(bsum, offs);
    k_scanC<<<dim3(SCB, RR), 256, 0, stream>>>(indeg, bsum, offs);
    k_norms<<<(RR * NN + 255) / 256, 256, 0, stream>>>(outdeg, indeg);
    int histBlocks = (RR * EE + 255) / 256;
    k_fillw<<<histBlocks, 256, 0, stream>>>(src, dst, offs, ns, cursor, csrw);
    k_bsum<<<1, 256, 0, stream>>>(b2a, b2b, b3a, b3b, bsums);
    k_mcat<<<17, 256, 0, stream>>>(Wp1, Wp2, bp1, bp2, Mcat, cvec);

    k_cast<<<(NN * 256 + 255) / 256, 256, 0, stream>>>(x2, XH, NN * 256);
    k_wt<<<(256 * RR * 256 + 255) / 256, 256, 0, stream>>>(W2a, WT2a, 256, 256, 256);
    k_wt<<<(128 * RR * 256 + 255) / 256, 256, 0, stream>>>(W2b, WT2b, 256, 256, 128);
    k_wt<<<(256 * RR * 304 + 255) / 256, 256, 0, stream>>>(W3a, WT3a, 300, 304, 256);
    k_wt<<<(128 * RR * 256 + 255) / 256, 256, 0, stream>>>(W3b, WT3b, 256, 256, 128);

    const int CH = 10000;                  // node chunk (5 chunks)
    dim3 gChunkA((CH + 127) / 128, 4);     // layer-a GEMM: BN=64, Nout=256
    dim3 gChunkB((CH + 127) / 128, 2);     // layer-b GEMM: BN=64, Nout=128

    // ---- layer 2a: hbuf = relu(sum_r agg_r(x2b) @ W2a_r + b) ----
    for (int c = 0; c < 5; c++) {
        int nb = c * CH;
        k_agg<64><<<dim3(CH / 4, 8), 256, 0, stream>>>(XH, 256, 64, 64, csrw, offs, nd,
                                                       0, nb, Y, 256, 2048);
        k_gemm_bf<2><<<gChunkA, 256, 0, stream>>>(Y, 2048, WT2a, 2048, bsums + 0,
                                                  feat, 256, (void*)(hbuf + (size_t)nb * 256), 256,
                                                  CH, 2048, 1 | 4 | 8);
    }
    // ---- layer 2b: feat[:, :128] ----
    for (int c = 0; c < 5; c++) {
        int nb = c * CH;
        k_agg<64><<<dim3(CH / 4, 8), 256, 0, stream>>>(hbuf, 256, 64, 64, csrw, offs, nd,
                                                       0, nb, Y, 256, 2048);
        k_gemm_bf<2><<<gChunkB, 256, 0, stream>>>(Y, 2048, WT2b, 2048, bsums + 256,
                                                  feat, 256, (void*)(feat + (size_t)nb * 256), 256,
                                                  CH, 2048, 1);
    }
    // ---- layer 3a (x3: din 300) ----
    k_cast<<<(NN * 300 + 255) / 256, 256, 0, stream>>>(x3, XH, NN * 300);
    for (int c = 0; c < 5; c++) {
        int nb = c * CH;
        k_agg<128><<<dim3(CH / 2, 8), 256, 0, stream>>>(XH, 300, 75, 76, csrw, offs, nd,
                                                        0, nb, Y, 304, 2432);
        k_gemm_bf<2><<<gChunkA, 256, 0, stream>>>(Y, 2432, WT3a, 2432, bsums + 512,
                                                  feat, 256, (void*)(hbuf + (size_t)nb * 256), 256,
                                                  CH, 2432, 1 | 4 | 8);
    }
    // ---- layer 3b: feat[:, 128:] ----
    for (int c = 0; c < 5; c++) {
        int nb = c * CH;
        k_agg<64><<<dim3(CH / 4, 8), 256, 0, stream>>>(hbuf, 256, 64, 64, csrw, offs, nd,
                                                       0, nb, Y, 256, 2048);
        k_gemm_bf<2><<<gChunkB, 256, 0, stream>>>(Y, 2048, WT3b, 2048, bsums + 768,
                                                  feat, 256, (void*)(feat + (size_t)nb * 256 + 128), 256,
                                                  CH, 2048, 1);
    }

    // ---- decoder ----
    k_ab<<<NN / 16, 256, 0, stream>>>(feat, Mcat, AB);
    k_dec<<<(EDD * 8 + 255) / 256, 256, 0, stream>>>(dsrc, ddst, AB, cvec, out);
}

// Round 7
// 1817.732 us; speedup vs baseline: 1.2246x; 1.1368x over previous
//
#include <hip/hip_runtime.h>
#include <hip/hip_bf16.h>

#define NN 50000
#define RR 8
#define EE 200000
#define EDD 400000
#define SCB 196   // ceil(NN/256) scan blocks

typedef __attribute__((ext_vector_type(8))) short short8;
typedef __attribute__((ext_vector_type(4))) float floatx4;

static __device__ __forceinline__ unsigned short f2bf(float f) {
    union { float f; unsigned u; } v; v.f = f;
    unsigned r = v.u + 0x7fff + ((v.u >> 16) & 1);
    return (unsigned short)(r >> 16);
}
static __device__ __forceinline__ float bf2f(unsigned short h) {
    union { unsigned u; float f; } v; v.u = ((unsigned)h) << 16;
    return v.f;
}
// async global->LDS, 16B per lane; LDS dest = uniform base + lane*16
static __device__ __forceinline__ void gload_lds16(const unsigned short* g, unsigned short* l) {
    __builtin_amdgcn_global_load_lds(
        (const __attribute__((address_space(1))) void*)g,
        (__attribute__((address_space(3))) void*)l,
        16, 0, 0);
}

// ---------------- LDS-privatized degree histogram ----------------
// grid (8 edge-chunks, RR, 4: z = which*2 + node-half). 16-bit packed LDS bins.
__global__ __launch_bounds__(256) void k_hist2(const int* __restrict__ src, const int* __restrict__ dst,
                        int* __restrict__ outdeg, int* __restrict__ indeg) {
    __shared__ unsigned lh[12500];   // 25000 nodes, 2 per word
    int chunk = blockIdx.x, r = blockIdx.y;
    int which = blockIdx.z >> 1, half = blockIdx.z & 1;
    const int* idx = (which ? dst : src) + (size_t)r * EE;
    int* deg = (which ? indeg : outdeg) + (size_t)r * NN;
    for (int i = threadIdx.x; i < 12500; i += 256) lh[i] = 0;
    __syncthreads();
    int e0 = chunk * (EE / 8);
    int lo = half * 25000;
    for (int e = e0 + threadIdx.x; e < e0 + EE / 8; e += 256) {
        int n = idx[e] - lo;
        if ((unsigned)n < 25000u)
            atomicAdd(&lh[n >> 1], 1u << ((n & 1) * 16));
    }
    __syncthreads();
    for (int i = threadIdx.x; i < 12500; i += 256) {
        unsigned v = lh[i];
        unsigned c0 = v & 0xffffu, c1 = v >> 16;
        if (c0) atomicAdd(&deg[lo + i * 2], (int)c0);
        if (c1) atomicAdd(&deg[lo + i * 2 + 1], (int)c1);
    }
}

// ---------------- norms: in-place int degree -> float rsqrt ----------------
__global__ void k_norms(int* __restrict__ outdeg, int* __restrict__ indeg) {
    int i = blockIdx.x * blockDim.x + threadIdx.x;
    if (i >= RR * NN) return;
    int od = outdeg[i];
    int id = indeg[i];
    ((float*)outdeg)[i] = od > 0 ? rsqrtf((float)od) : 0.f;
    ((float*)indeg)[i]  = id > 0 ? rsqrtf((float)id) : 0.f;
}

// ---------------- parallel scan: phase A (per-block sums) ----------------
__global__ void k_scanA(const int* __restrict__ indeg, int* __restrict__ bsum) {
    int r = blockIdx.y;
    int i = blockIdx.x * 256 + threadIdx.x;
    int v = (i < NN) ? indeg[(size_t)r * NN + i] : 0;
    #pragma unroll
    for (int d = 32; d > 0; d >>= 1) v += __shfl_down(v, d, 64);
    __shared__ int ws4[4];
    if ((threadIdx.x & 63) == 0) ws4[threadIdx.x >> 6] = v;
    __syncthreads();
    if (threadIdx.x == 0) bsum[r * SCB + blockIdx.x] = ws4[0] + ws4[1] + ws4[2] + ws4[3];
}

// ---------------- phase B: exclusive scan of SCB block sums per relation ----------------
__global__ void k_scanB(int* __restrict__ bsum, int* __restrict__ offs) {
    int r = blockIdx.x;
    int t = threadIdx.x;
    int v = (t < SCB) ? bsum[r * SCB + t] : 0;
    int lane = t & 63, wid = t >> 6;
    int sv = v;
    #pragma unroll
    for (int d = 1; d < 64; d <<= 1) {
        int u = __shfl_up(sv, d, 64);
        if (lane >= d) sv += u;
    }
    __shared__ int wsum[4];
    if (lane == 63) wsum[wid] = sv;
    __syncthreads();
    int add = 0;
    for (int x = 0; x < wid; x++) add += wsum[x];
    int incl = sv + add;
    if (t < SCB) bsum[r * SCB + t] = incl - v;
    if (t == 255) offs[(size_t)r * (NN + 1) + NN] = incl;  // grand total
}

// ---------------- phase C: intra-block exclusive scan + base ----------------
__global__ void k_scanC(const int* __restrict__ indeg, const int* __restrict__ bsum,
                        int* __restrict__ offs) {
    int r = blockIdx.y;
    int i = blockIdx.x * 256 + threadIdx.x;
    int v = (i < NN) ? indeg[(size_t)r * NN + i] : 0;
    int lane = threadIdx.x & 63, wid = threadIdx.x >> 6;
    int sv = v;
    #pragma unroll
    for (int d = 1; d < 64; d <<= 1) {
        int u = __shfl_up(sv, d, 64);
        if (lane >= d) sv += u;
    }
    __shared__ int wsum[4];
    if (lane == 63) wsum[wid] = sv;
    __syncthreads();
    int add = bsum[r * SCB + blockIdx.x];
    for (int x = 0; x < wid; x++) add += wsum[x];
    if (i < NN) offs[(size_t)r * (NN + 1) + i] = sv - v + add;
}

// ---------------- fill CSR with fused src-norm weight: (src, ns[r][src]) ----------------
__global__ void k_fillw(const int* __restrict__ src, const int* __restrict__ dst,
                        const int* __restrict__ offs, const float* __restrict__ ns,
                        int* __restrict__ cursor, int2* __restrict__ csrw) {
    int i = blockIdx.x * blockDim.x + threadIdx.x;
    if (i >= RR * EE) return;
    int r = i / EE;
    int s = src[i], d = dst[i];
    int pos = offs[r * (NN + 1) + d] + atomicAdd(&cursor[r * NN + d], 1);
    int2 v;
    v.x = s;
    v.y = __float_as_int(ns[(size_t)r * NN + s]);
    csrw[(size_t)r * EE + pos] = v;
}

// ---------------- decoder prep (Mcat, cvec) + bias sums, one launch ----------------
__global__ void k_prep(const float* __restrict__ Wp1, const float* __restrict__ Wp2,
                       const float* __restrict__ bp1, const float* __restrict__ bp2,
                       const float* __restrict__ b2a, const float* __restrict__ b2b,
                       const float* __restrict__ b3a, const float* __restrict__ b3b,
                       float* __restrict__ Mcat, float* __restrict__ cvec,
                       float* __restrict__ bs) {
    int bx = blockIdx.x;
    if (bx < 16) {
        int t = bx * 256 + threadIdx.x;      // 4096 elements
        int i = t >> 4, j = t & 15;
        int half = j >> 3, jj = j & 7;
        const float* wrow = Wp1 + (size_t)(half * 256 + i) * 256;
        float s = 0.f;
        for (int k = 0; k < 256; k++) s += wrow[k] * Wp2[k * 8 + jj];
        Mcat[i * 16 + j] = s;
    } else if (bx == 16) {
        int j = threadIdx.x;
        if (j < 8) {
            float s = bp2[j];
            for (int k = 0; k < 256; k++) s += bp1[k] * Wp2[k * 8 + j];
            cvec[j] = s;
        }
    } else {
        int j = threadIdx.x;  // 256
        float s = 0.f;
        for (int r = 0; r < RR; r++) s += b2a[r * 256 + j];
        bs[j] = s;
        if (j < 128) {
            s = 0.f;
            for (int r = 0; r < RR; r++) s += b2b[r * 128 + j];
            bs[256 + j] = s;
        }
        s = 0.f;
        for (int r = 0; r < RR; r++) s += b3a[r * 256 + j];
        bs[512 + j] = s;
        if (j < 128) {
            s = 0.f;
            for (int r = 0; r < RR; r++) s += b3b[r * 128 + j];
            bs[768 + j] = s;
        }
    }
}

// ---------------- fp32 -> bf16 elementwise cast ----------------
__global__ void k_cast(const float* __restrict__ x, unsigned short* __restrict__ y, int total) {
    int i = blockIdx.x * blockDim.x + threadIdx.x;
    if (i < total) y[i] = f2bf(x[i]);
}

// ---------------- all 4 weight transposes in one launch ----------------
__global__ void k_wt4(const float* __restrict__ W2a, const float* __restrict__ W2b,
                      const float* __restrict__ W3a, const float* __restrict__ W3b,
                      unsigned short* __restrict__ WT2a, unsigned short* __restrict__ WT2b,
                      unsigned short* __restrict__ WT3a, unsigned short* __restrict__ WT3b) {
    const float* W; unsigned short* WT; int K0, Kpad, Nout;
    switch (blockIdx.y) {
        case 0:  W = W2a; WT = WT2a; K0 = 256; Kpad = 256; Nout = 256; break;
        case 1:  W = W2b; WT = WT2b; K0 = 256; Kpad = 256; Nout = 128; break;
        case 2:  W = W3a; WT = WT3a; K0 = 300; Kpad = 304; Nout = 256; break;
        default: W = W3b; WT = WT3b; K0 = 256; Kpad = 256; Nout = 128; break;
    }
    int i = blockIdx.x * 256 + threadIdx.x;
    int total = Nout * RR * Kpad;
    if (i >= total) return;
    int n = i / (RR * Kpad);
    int rem = i - n * (RR * Kpad);
    int r = rem / Kpad;
    int k = rem - r * Kpad;
    float v = (k < K0) ? W[((size_t)r * K0 + k) * Nout + n] : 0.f;
    WT[i] = f2bf(v);
}

// ---------------- aggregation: wave per (node, relation), scalarized edge records ----------------
// 64 lanes per node, 4 nodes per block. EXTRA=1: lanes 0..din4-65 handle a second chunk (300-dim).
template<int EXTRA>
__global__ __launch_bounds__(256) void k_agg(
        const unsigned short* __restrict__ xb, int xstride, int din4,
        const int2* __restrict__ csrw, const int* __restrict__ offs,
        const float* __restrict__ nd, int nbase,
        unsigned short* __restrict__ Y, int Kpad, int ystride) {
    int lane = threadIdx.x & 63;
    int sub = threadIdx.x >> 6;
    int bn = blockIdx.x * 4 + sub;
    int n = nbase + bn;
    int r = blockIdx.y;
    int o0 = offs[r * (NN + 1) + n];
    int o1 = offs[r * (NN + 1) + n + 1];
    o0 = __builtin_amdgcn_readfirstlane(o0);   // wave-uniform: scalarize edge loop
    o1 = __builtin_amdgcn_readfirstlane(o1);
    float ndv = nd[(size_t)r * NN + n];
    const int2* cs = csrw + (size_t)r * EE;
    bool ex = EXTRA && (lane + 64 < din4);
    float a0 = 0.f, a1 = 0.f, a2 = 0.f, a3 = 0.f;
    float b0 = 0.f, b1 = 0.f, b2 = 0.f, b3 = 0.f;
    int e = o0;
    for (; e + 4 <= o1; e += 4) {
        int2 w0 = cs[e], w1 = cs[e + 1], w2 = cs[e + 2], w3 = cs[e + 3];
        const unsigned short* p0 = xb + (size_t)(unsigned)w0.x * xstride;
        const unsigned short* p1 = xb + (size_t)(unsigned)w1.x * xstride;
        const unsigned short* p2 = xb + (size_t)(unsigned)w2.x * xstride;
        const unsigned short* p3 = xb + (size_t)(unsigned)w3.x * xstride;
        ushort4 v0 = *(const ushort4*)(p0 + lane * 4);
        ushort4 v1 = *(const ushort4*)(p1 + lane * 4);
        ushort4 v2 = *(const ushort4*)(p2 + lane * 4);
        ushort4 v3 = *(const ushort4*)(p3 + lane * 4);
        float f0 = __int_as_float(w0.y), f1 = __int_as_float(w1.y);
        float f2 = __int_as_float(w2.y), f3 = __int_as_float(w3.y);
        a0 += f0 * bf2f(v0.x) + f1 * bf2f(v1.x) + f2 * bf2f(v2.x) + f3 * bf2f(v3.x);
        a1 += f0 * bf2f(v0.y) + f1 * bf2f(v1.y) + f2 * bf2f(v2.y) + f3 * bf2f(v3.y);
        a2 += f0 * bf2f(v0.z) + f1 * bf2f(v1.z) + f2 * bf2f(v2.z) + f3 * bf2f(v3.z);
        a3 += f0 * bf2f(v0.w) + f1 * bf2f(v1.w) + f2 * bf2f(v2.w) + f3 * bf2f(v3.w);
        if (EXTRA && ex) {
            ushort4 u0 = *(const ushort4*)(p0 + (lane + 64) * 4);
            ushort4 u1 = *(const ushort4*)(p1 + (lane + 64) * 4);
            ushort4 u2 = *(const ushort4*)(p2 + (lane + 64) * 4);
            ushort4 u3 = *(const ushort4*)(p3 + (lane + 64) * 4);
            b0 += f0 * bf2f(u0.x) + f1 * bf2f(u1.x) + f2 * bf2f(u2.x) + f3 * bf2f(u3.x);
            b1 += f0 * bf2f(u0.y) + f1 * bf2f(u1.y) + f2 * bf2f(u2.y) + f3 * bf2f(u3.y);
            b2 += f0 * bf2f(u0.z) + f1 * bf2f(u1.z) + f2 * bf2f(u2.z) + f3 * bf2f(u3.z);
            b3 += f0 * bf2f(u0.w) + f1 * bf2f(u1.w) + f2 * bf2f(u2.w) + f3 * bf2f(u3.w);
        }
    }
    for (; e < o1; e++) {
        int2 w0 = cs[e];
        const unsigned short* p0 = xb + (size_t)(unsigned)w0.x * xstride;
        ushort4 v0 = *(const ushort4*)(p0 + lane * 4);
        float f0 = __int_as_float(w0.y);
        a0 += f0 * bf2f(v0.x); a1 += f0 * bf2f(v0.y);
        a2 += f0 * bf2f(v0.z); a3 += f0 * bf2f(v0.w);
        if (EXTRA && ex) {
            ushort4 u0 = *(const ushort4*)(p0 + (lane + 64) * 4);
            b0 += f0 * bf2f(u0.x); b1 += f0 * bf2f(u0.y);
            b2 += f0 * bf2f(u0.z); b3 += f0 * bf2f(u0.w);
        }
    }
    unsigned short* yp = Y + (size_t)bn * ystride + (size_t)r * Kpad;
    ushort4 o;
    o.x = f2bf(a0 * ndv); o.y = f2bf(a1 * ndv);
    o.z = f2bf(a2 * ndv); o.w = f2bf(a3 * ndv);
    *(ushort4*)(yp + lane * 4) = o;
    if (EXTRA && ex) {
        ushort4 o2;
        o2.x = f2bf(b0 * ndv); o2.y = f2bf(b1 * ndv);
        o2.z = f2bf(b2 * ndv); o2.w = f2bf(b3 * ndv);
        *(ushort4*)(yp + (lane + 64) * 4) = o2;
    }
}

// ---------------- bf16 MFMA GEMM, async-LDS staged, XOR-swizzled ----------------
// Tile 128 x (TN*32). A [M x K] bf16 (lda), BT [Nout x K] bf16 (ldb).
// flags: 1=addbias, 2=accum(read Cin fp32), 4=relu, 8=out bf16 (else fp32)
template<int TN>
__global__ __launch_bounds__(256) void k_gemm_bf(
        const unsigned short* __restrict__ A, int lda,
        const unsigned short* __restrict__ BT, int ldb,
        const float* __restrict__ bias,
        const float* __restrict__ Cin, int ldcin,
        void* __restrict__ Cout, int ldc,
        int M, int K, int flags) {
    constexpr int BN = TN * 32;
    __shared__ unsigned short As[128 * 64];
    __shared__ unsigned short Bs[BN * 64];
    int m0 = blockIdx.x * 128;
    int n0 = blockIdx.y * BN;
    int t = threadIdx.x;
    int w = t >> 6, l = t & 63;
    int qm = (w >> 1) * 64, qn = (w & 1) * (TN * 16);
    int lr = l & 15, lg = l >> 4;
    int lrow = l >> 3;            // row within 8-row segment
    int lch  = (l & 7) ^ lrow;    // swizzled source chunk (8 bf16 each)

    floatx4 acc[4][TN];
    #pragma unroll
    for (int a = 0; a < 4; a++)
        #pragma unroll
        for (int b = 0; b < TN; b++)
            acc[a][b] = (floatx4){0.f, 0.f, 0.f, 0.f};

    for (int k0 = 0; k0 < K; k0 += 64) {
        #pragma unroll
        for (int j = 0; j < 4; j++) {
            int seg = w * 4 + j;              // 16 segments x 8 rows = 128 rows
            int gr = m0 + seg * 8 + lrow; if (gr > M - 1) gr = M - 1;
            gload_lds16(A + (size_t)gr * lda + k0 + lch * 8, &As[seg * 512]);
        }
        #pragma unroll
        for (int j = 0; j < TN; j++) {
            int seg = w * TN + j;             // BN/8 segments
            int row = n0 + seg * 8 + lrow;
            gload_lds16(BT + (size_t)row * ldb + k0 + lch * 8, &Bs[seg * 512]);
        }
        __syncthreads();
        #pragma unroll
        for (int ks = 0; ks < 2; ks++) {
            int slot = ((ks * 4 + lg) ^ (lr & 7)) * 8;
            short8 af[4], bf[TN];
            #pragma unroll
            for (int i = 0; i < 4; i++)
                af[i] = *(const short8*)&As[(qm + i * 16 + lr) * 64 + slot];
            #pragma unroll
            for (int i = 0; i < TN; i++)
                bf[i] = *(const short8*)&Bs[(qn + i * 16 + lr) * 64 + slot];
            #pragma unroll
            for (int tm = 0; tm < 4; tm++)
                #pragma unroll
                for (int tn = 0; tn < TN; tn++)
                    acc[tm][tn] = __builtin_amdgcn_mfma_f32_16x16x32_bf16(
                        af[tm], bf[tn], acc[tm][tn], 0, 0, 0);
        }
        __syncthreads();
    }

    int addbias = flags & 1, accum = flags & 2, relu = flags & 4, outbf = flags & 8;
    #pragma unroll
    for (int tm = 0; tm < 4; tm++) {
        int rbase = m0 + qm + tm * 16 + lg * 4;
        #pragma unroll
        for (int reg = 0; reg < 4; reg++) {
            int row = rbase + reg;
            if (row >= M) continue;
            #pragma unroll
            for (int tn = 0; tn < TN; tn++) {
                int col = n0 + qn + tn * 16 + lr;
                float v = acc[tm][tn][reg];
                if (addbias) v += bias[col];
                if (accum) v += Cin[(size_t)row * ldcin + col];
                if (relu) v = fmaxf(v, 0.f);
                if (outbf) ((unsigned short*)Cout)[(size_t)row * ldc + col] = f2bf(v);
                else       ((float*)Cout)[(size_t)row * ldc + col] = v;
            }
        }
    }
}

// ---------------- AB = feat @ Mcat  [N x 16] (float4 loads) ----------------
__global__ void k_ab(const float* __restrict__ feat, const float* __restrict__ Mcat,
                     float* __restrict__ AB) {
    __shared__ float Ms[4096];
    int t = threadIdx.x;
    for (int i = t; i < 4096; i += 256) Ms[i] = Mcat[i];
    __syncthreads();
    int n = blockIdx.x * 16 + (t >> 4);
    int c = t & 15;
    const float4* fr = (const float4*)(feat + (size_t)n * 256);
    float s = 0.f;
    #pragma unroll 8
    for (int k4 = 0; k4 < 64; k4++) {
        float4 v = fr[k4];
        s += v.x * Ms[(k4 * 4 + 0) * 16 + c] + v.y * Ms[(k4 * 4 + 1) * 16 + c]
           + v.z * Ms[(k4 * 4 + 2) * 16 + c] + v.w * Ms[(k4 * 4 + 3) * 16 + c];
    }
    AB[(size_t)n * 16 + c] = s;
}

// ---------------- per-edge decoder ----------------
__global__ void k_dec(const int* __restrict__ dsrc, const int* __restrict__ ddst,
                      const float* __restrict__ AB, const float* __restrict__ cvec,
                      float* __restrict__ out) {
    int i = blockIdx.x * blockDim.x + threadIdx.x;
    if (i >= EDD * 8) return;
    int e = i >> 3, k = i & 7;
    out[i] = AB[dsrc[e] * 16 + k] + AB[ddst[e] * 16 + 8 + k] + cvec[k];
}

extern "C" void kernel_launch(void* const* d_in, const int* in_sizes, int n_in,
                              void* d_out, int out_size, void* d_ws, size_t ws_size,
                              hipStream_t stream) {
    const float* x2  = (const float*)d_in[0];
    const float* x3  = (const float*)d_in[1];
    const int*   src = (const int*)d_in[2];
    const int*   dst = (const int*)d_in[3];
    const int*   dsrc = (const int*)d_in[4];
    const int*   ddst = (const int*)d_in[5];
    const float* W2a = (const float*)d_in[6];
    const float* b2a = (const float*)d_in[7];
    const float* W2b = (const float*)d_in[8];
    const float* b2b = (const float*)d_in[9];
    const float* W3a = (const float*)d_in[10];
    const float* b3a = (const float*)d_in[11];
    const float* W3b = (const float*)d_in[12];
    const float* b3b = (const float*)d_in[13];
    const float* Wp1 = (const float*)d_in[14];
    const float* bp1 = (const float*)d_in[15];
    const float* Wp2 = (const float*)d_in[16];
    const float* bp2 = (const float*)d_in[17];
    float* out = (float*)d_out;

    // ---- workspace layout (~176 MB, < proven 182.4 MB bound) ----
    char* ws = (char*)d_ws;
    size_t off = 0;
    auto alloc = [&](size_t nbytes) {
        char* p = ws + off;
        off += nbytes;
        off = (off + 255) & ~(size_t)255;
        return p;
    };
    float* ns   = (float*)alloc((size_t)RR * NN * 4);        // aliases outdeg
    float* nd   = (float*)alloc((size_t)RR * NN * 4);        // aliases indeg
    int*   offs = (int*)alloc((size_t)RR * (NN + 1) * 4);
    int2*  csrw = (int2*)alloc((size_t)RR * EE * 8);
    unsigned short* XH   = (unsigned short*)alloc((size_t)NN * 300 * 2);  // x2b then x3b
    unsigned short* hbuf = (unsigned short*)alloc((size_t)NN * 256 * 2);  // layer-a out; AB aliases
    unsigned short* WT2a = (unsigned short*)alloc((size_t)256 * 2048 * 2);
    unsigned short* WT2b = (unsigned short*)alloc((size_t)128 * 2048 * 2);
    unsigned short* WT3a = (unsigned short*)alloc((size_t)256 * 2432 * 2);
    unsigned short* WT3b = (unsigned short*)alloc((size_t)128 * 2048 * 2);
    unsigned short* Y    = (unsigned short*)alloc((size_t)10000 * 2432 * 2);  // cursor aliases head
    float* feat  = (float*)alloc((size_t)NN * 256 * 4);
    float* bsums = (float*)alloc(1024 * 4);
    float* Mcat  = (float*)alloc(4096 * 4);
    float* cvec  = (float*)alloc(64 * 4);
    int*   bsum  = (int*)alloc((size_t)RR * SCB * 4);

    int*   outdeg = (int*)ns;
    int*   indeg  = (int*)nd;
    int*   cursor = (int*)Y;       // only live during k_fillw (before any Y use)
    float* AB     = (float*)hbuf;  // only live after last hbuf read

    // ---- graph prep ----
    hipMemsetAsync(outdeg, 0, (size_t)RR * NN * 4, stream);
    hipMemsetAsync(indeg,  0, (size_t)RR * NN * 4, stream);
    hipMemsetAsync(cursor, 0, (size_t)RR * NN * 4, stream);

    k_hist2<<<dim3(8, RR, 4), 256, 0, stream>>>(src, dst, outdeg, indeg);
    k_scanA<<<dim3(SCB, RR), 256, 0, stream>>>(indeg, bsum);
    k_scanB<<<RR, 256, 0, stream>>>(bsum, offs);
    k_scanC<<<dim3(SCB, RR), 256, 0, stream>>>(indeg, bsum, offs);
    k_norms<<<(RR * NN + 255) / 256, 256, 0, stream>>>(outdeg, indeg);
    int histBlocks = (RR * EE + 255) / 256;
    k_fillw<<<histBlocks, 256, 0, stream>>>(src, dst, offs, ns, cursor, csrw);
    k_prep<<<18, 256, 0, stream>>>(Wp1, Wp2, bp1, bp2, b2a, b2b, b3a, b3b, Mcat, cvec, bsums);

    k_cast<<<(NN * 256 + 255) / 256, 256, 0, stream>>>(x2, XH, NN * 256);
    k_wt4<<<dim3(2432, 4), 256, 0, stream>>>(W2a, W2b, W3a, W3b, WT2a, WT2b, WT3a, WT3b);

    const int CH = 10000;                  // node chunk (5 chunks)
    dim3 gChunkA((CH + 127) / 128, 4);     // layer-a GEMM: BN=64, Nout=256 -> 316 blocks
    dim3 gChunkB((CH + 127) / 128, 4);     // layer-b GEMM: BN=32, Nout=128 -> 316 blocks

    // ---- layer 2a: hbuf = relu(sum_r agg_r(x2b) @ W2a_r + b) ----
    for (int c = 0; c < 5; c++) {
        int nb = c * CH;
        k_agg<0><<<dim3(CH / 4, 8), 256, 0, stream>>>(XH, 256, 64, csrw, offs, nd,
                                                      nb, Y, 256, 2048);
        k_gemm_bf<2><<<gChunkA, 256, 0, stream>>>(Y, 2048, WT2a, 2048, bsums + 0,
                                                  feat, 256, (void*)(hbuf + (size_t)nb * 256), 256,
                                                  CH, 2048, 1 | 4 | 8);
    }
    // ---- layer 2b: feat[:, :128] ----
    for (int c = 0; c < 5; c++) {
        int nb = c * CH;
        k_agg<0><<<dim3(CH / 4, 8), 256, 0, stream>>>(hbuf, 256, 64, csrw, offs, nd,
                                                      nb, Y, 256, 2048);
        k_gemm_bf<1><<<gChunkB, 256, 0, stream>>>(Y, 2048, WT2b, 2048, bsums + 256,
                                                  feat, 256, (void*)(feat + (size_t)nb * 256), 256,
                                                  CH, 2048, 1);
    }
    // ---- layer 3a (x3: din 300) ----
    k_cast<<<(NN * 300 + 255) / 256, 256, 0, stream>>>(x3, XH, NN * 300);
    for (int c = 0; c < 5; c++) {
        int nb = c * CH;
        k_agg<1><<<dim3(CH / 4, 8), 256, 0, stream>>>(XH, 300, 75, csrw, offs, nd,
                                                      nb, Y, 304, 2432);
        k_gemm_bf<2><<<gChunkA, 256, 0, stream>>>(Y, 2432, WT3a, 2432, bsums + 512,
                                                  feat, 256, (void*)(hbuf + (size_t)nb * 256), 256,
                                                  CH, 2432, 1 | 4 | 8);
    }
    // ---- layer 3b: feat[:, 128:] ----
    for (int c = 0; c < 5; c++) {
        int nb = c * CH;
        k_agg<0><<<dim3(CH / 4, 8), 256, 0, stream>>>(hbuf, 256, 64, csrw, offs, nd,
                                                      nb, Y, 256, 2048);
        k_gemm_bf<1><<<gChunkB, 256, 0, stream>>>(Y, 2048, WT3b, 2048, bsums + 768,
                                                  feat, 256, (void*)(feat + (size_t)nb * 256 + 128), 256,
                                                  CH, 2048, 1);
    }

    // ---- decoder ----
    k_ab<<<NN / 16, 256, 0, stream>>>(feat, Mcat, AB);
    k_dec<<<(EDD * 8 + 255) / 256, 256, 0, stream>>>(dsrc, ddst, AB, cvec, out);
}